// Round 10
// baseline (470.376 us; speedup 1.0000x reference)
//
#include <hip/hip_runtime.h>

// ---------------------------------------------------------------------------
// T5GNNAdapt: LN -> RGCN scatter-mean (2 relations) -> [h0|h1|x] @ [W0;W1;root]
//             + bias -> relu -> @wo -> + residual
// Shapes: B=8,S=1024,D=1024,F=4096,E=262144,N=B*S=8192, K_cat=3072
// R7:  gemm1 -> 256^2 8-phase counted-vmcnt template.
// R8:  gemm2 -> same template. R9: FAILED A-prefetch (reverted); agg wave/bkt.
// R10: gemm1 LDS epilogue; count fused into ln.
// R11: lgkmcnt(0) drain removed + FENCE; gemm2 LDS epilogue. 459us.
// R12: agg+cvt fusion + readlane/pk-add aggregate. 452.8 (-6.4, sub-falsifier).
// R13: gemm2 triple-buffer VM6. 449.8 (-3.0, sub-falsifier -> gemm2 near its
//      structural floor; non-gemm1 budget models keep over-estimating).
// R14: gemm1 MFMA shape 16x16x32 -> 32x32x16 (m119: 4060 vs 3380 FLOP/cyc,
//      17% fewer matrix-pipe cycles; half the MFMA instructions). Schedule,
//      staging, barriers, VM4 placement, LDS swizzle all UNCHANGED — only
//      fragment indexing, accumulator (f32x16 acc[4][2]), and epilogue
//      mapping (C/D: col=l&31, row=(r&3)+8*(r>>2)+4*(l>>5), m74/m101) change.
// ---------------------------------------------------------------------------

typedef unsigned short u16;
typedef unsigned int   u32;
typedef __attribute__((ext_vector_type(8))) short bf16x8;
typedef __attribute__((ext_vector_type(4))) float f32x4;
typedef __attribute__((ext_vector_type(2))) float f32x2;
typedef __attribute__((ext_vector_type(16))) float f32x16;

#define E_NUM  262144
#define NNODE  8192
#define NBKT   (2 * NNODE)      // 16384 (rel,dst) buckets
#define DDIM   1024
#define FDIM   4096
#define KCAT   3072
#define LN_EPS 1e-6f

#define AGG_BLOCKS  (NBKT / 4)                     // 4096
#define CVT1_BLOCKS ((FDIM / 32) * (KCAT / 32))    // 12288
#define CVT2_BLOCKS ((DDIM / 32) * (FDIM / 32))    // 4096

struct alignas(8) u16x4 { u16 x, y, z, w; };

__device__ __forceinline__ u16 f2bf(float f) {
  u32 u = __float_as_uint(f);
  u32 r = u + 0x7fffu + ((u >> 16) & 1u);   // RNE
  return (u16)(r >> 16);
}
__device__ __forceinline__ float bf2f(u16 h) {
  return __uint_as_float(((u32)h) << 16);
}

// ---- fp8 e4m3fn (OCP) encode/decode; HW cvt when available ---------------
__device__ __forceinline__ u32 enc_fp8_1(float f) {
  u32 u = __float_as_uint(f);
  u32 s = u >> 31;
  u32 mag = u & 0x7fffffffu;
  mag = mag + 0x7ffffu + ((mag >> 20) & 1u);          // RNE to 3 mant bits
  if (mag > 0x43e00000u) mag = 0x43e00000u;           // clamp to 448
  u32 e = mag >> 23;
  return (e <= 120u) ? 0u
                     : ((s << 7) | ((e - 120u) << 3) | ((mag >> 20) & 7u));
}

__device__ __forceinline__ u32 pack4_fp8(float a, float b, float c, float d) {
#if __has_builtin(__builtin_amdgcn_cvt_pk_fp8_f32)
  int v = 0;
  v = __builtin_amdgcn_cvt_pk_fp8_f32(a, b, v, false);  // bytes 0,1
  v = __builtin_amdgcn_cvt_pk_fp8_f32(c, d, v, true);   // bytes 2,3
  return (u32)v;
#else
  return enc_fp8_1(a) | (enc_fp8_1(b) << 8) | (enc_fp8_1(c) << 16) |
         (enc_fp8_1(d) << 24);
#endif
}

__device__ __forceinline__ float dec_fp8_1(u32 b) {
  u32 e = (b >> 3) & 15u;
  u32 f = ((b & 0x80u) << 24) | ((e + 120u) << 23) | ((b & 7u) << 20);
  return e ? __uint_as_float(f) : 0.0f;
}

template <bool HI>
__device__ __forceinline__ f32x2 cvt2_fp8(u32 q) {
#if __has_builtin(__builtin_amdgcn_cvt_pk_f32_fp8)
  return __builtin_amdgcn_cvt_pk_f32_fp8((int)q, HI);   // HI is an immediate
#else
  f32x2 r;
  const u32 sh = HI ? 16u : 0u;
  r.x = dec_fp8_1((q >> sh) & 0xffu);
  r.y = dec_fp8_1((q >> (sh + 8)) & 0xffu);
  return r;
#endif
}

// accumulate one dwordx4 (16 fp8) into 8 f32x2 accumulators (pk adds)
__device__ __forceinline__ void acc16q(f32x2* ac, uint4 q) {
  ac[0] += cvt2_fp8<false>(q.x); ac[1] += cvt2_fp8<true>(q.x);
  ac[2] += cvt2_fp8<false>(q.y); ac[3] += cvt2_fp8<true>(q.y);
  ac[4] += cvt2_fp8<false>(q.z); ac[5] += cvt2_fp8<true>(q.z);
  ac[6] += cvt2_fp8<false>(q.w); ac[7] += cvt2_fp8<true>(q.w);
}

// 16-byte global -> LDS async copy (wave-uniform LDS base + lane*16 layout)
#define GLD16(gp, lp)                                              \
  __builtin_amdgcn_global_load_lds(                                \
      (__attribute__((address_space(1))) u32*)(gp),                \
      (__attribute__((address_space(3))) u32*)(lp), 16, 0, 0)

// ---------------------------------------------------------------------------
// K1: LayerNorm (one-pass) + fused edge-count.
// ---------------------------------------------------------------------------
__global__ void ln_kernel(const float* __restrict__ hs,
                          const float* __restrict__ gamma,
                          const float* __restrict__ beta,
                          u16* __restrict__ hcat,
                          u32* __restrict__ xq,
                          const int* __restrict__ edge_index,
                          const int* __restrict__ edge_type,
                          int* __restrict__ cnt) {
  const int row = blockIdx.x;
  const int tid = threadIdx.x;
  const float4 v = ((const float4*)(hs + (size_t)row * DDIM))[tid];

  if (tid < 32) {                       // fused count: 32 edges per block
    const int e = (row << 5) + tid;
    const int d = edge_index[E_NUM + e];
    const int r = edge_type[e];
    atomicAdd(&cnt[r * NNODE + d], 1);
  }

  __shared__ float r1[256], r2[256];
  r1[tid] = v.x + v.y + v.z + v.w;
  r2[tid] = v.x * v.x + v.y * v.y + v.z * v.z + v.w * v.w;
  __syncthreads();
  for (int st = 128; st > 0; st >>= 1) {
    if (tid < st) { r1[tid] += r1[tid + st]; r2[tid] += r2[tid + st]; }
    __syncthreads();
  }
  const float mean = r1[0] * (1.0f / DDIM);
  const float var  = r2[0] * (1.0f / DDIM) - mean * mean;
  const float rs   = rsqrtf(var + LN_EPS);

  const int base = tid * 4;
  const float4 g = *(const float4*)(gamma + base);
  const float4 b = *(const float4*)(beta + base);
  const float o0 = (v.x - mean) * rs * g.x + b.x;
  const float o1 = (v.y - mean) * rs * g.y + b.y;
  const float o2 = (v.z - mean) * rs * g.z + b.z;
  const float o3 = (v.w - mean) * rs * g.w + b.w;
  u16x4 o;
  o.x = f2bf(o0); o.y = f2bf(o1); o.z = f2bf(o2); o.w = f2bf(o3);
  *(u16x4*)(hcat + (size_t)row * KCAT + 2048 + base) = o;
  xq[row * 256 + tid] = pack4_fp8(o0, o1, o2, o3);
}

// ---------------------------------------------------------------------------
// K3b: exclusive prefix sum over 16384 counts (single block, 1024 thr).
// ---------------------------------------------------------------------------
__global__ __launch_bounds__(1024) void scan_kernel(const int* __restrict__ cnt,
                                                    int* __restrict__ off,
                                                    int* __restrict__ cursor) {
  __shared__ int partial[1024];
  const int tid  = threadIdx.x;
  const int base = tid * 16;
  int local[16];
  int s = 0;
#pragma unroll
  for (int i = 0; i < 16; ++i) { local[i] = s; s += cnt[base + i]; }
  partial[tid] = s;
  __syncthreads();
  for (int st = 1; st < 1024; st <<= 1) {
    const int v = (tid >= st) ? partial[tid - st] : 0;
    __syncthreads();
    partial[tid] += v;
    __syncthreads();
  }
  const int pre = (tid == 0) ? 0 : partial[tid - 1];
#pragma unroll
  for (int i = 0; i < 16; ++i) {
    const int o = pre + local[i];
    off[base + i]    = o;
    cursor[base + i] = o;
  }
}

// ---------------------------------------------------------------------------
// K3c: scatter edge SOURCE ids into buckets (4B per edge, not row data).
// ---------------------------------------------------------------------------
__global__ void fill_kernel(const int* __restrict__ edge_index,
                            const int* __restrict__ edge_type,
                            int* __restrict__ cursor,
                            int* __restrict__ bucket_src) {
  const int e = blockIdx.x * 256 + threadIdx.x;
  const int s = edge_index[e];
  const int d = edge_index[E_NUM + e];
  const int r = edge_type[e];
  const int pos = atomicAdd(&cursor[r * NNODE + d], 1);
  bucket_src[pos] = s;
}

// ---------------------------------------------------------------------------
// K4: fused aggregate + weight transposes.
// ---------------------------------------------------------------------------
__device__ __forceinline__ void cvt_body(const float* __restrict__ srcA,
                                         const float* __restrict__ srcB,
                                         int splitK, int K, int N,
                                         u16* __restrict__ dst,
                                         int n0, int k0, int tx, int ty,
                                         float (*tile)[33]) {
  for (int i = ty; i < 32; i += 8) {
    const int k = k0 + i;
    const float v = (k < splitK) ? srcA[(size_t)k * N + n0 + tx]
                                 : srcB[(size_t)(k - splitK) * N + n0 + tx];
    tile[i][tx] = v;
  }
  __syncthreads();
  for (int i = ty; i < 32; i += 8) {
    dst[(size_t)(n0 + i) * K + k0 + tx] = f2bf(tile[tx][i]);
  }
}

__global__ __launch_bounds__(256) void agg_cvt_kernel(
    const int* __restrict__ cnt, const int* __restrict__ off,
    const int* __restrict__ bucket_src, const u32* __restrict__ xq,
    u16* __restrict__ hcat,
    const float* __restrict__ weight, const float* __restrict__ root,
    u16* __restrict__ WcatT,
    const float* __restrict__ wo, u16* __restrict__ woT) {
  __shared__ float tile[32][33];
  const int bx  = blockIdx.x;
  const int tid = threadIdx.x;

  if (bx >= AGG_BLOCKS) {
    const int tx = tid & 31, ty = tid >> 5;
    if (bx < AGG_BLOCKS + CVT1_BLOCKS) {
      const int idx = bx - AGG_BLOCKS;
      cvt_body(weight, root, 2048, KCAT, FDIM, WcatT,
               (idx & 127) * 32, (idx >> 7) * 32, tx, ty, tile);
    } else {
      const int idx = bx - AGG_BLOCKS - CVT1_BLOCKS;
      cvt_body(wo, wo, FDIM, FDIM, DDIM, woT,
               (idx & 31) * 32, (idx >> 5) * 32, tx, ty, tile);
    }
    return;
  }

  // ---- aggregate path ----
  const int b    = bx * 4 + (tid >> 6);   // bucket id
  const int lane = tid & 63;
  const int r    = b >> 13;
  const int node = b & (NNODE - 1);
  const int n     = cnt[b];
  const int start = off[b];

  f32x2 ac[8] = {};

#define LDROW(j) (*(const uint4*)(xq +                                     \
    (size_t)__builtin_amdgcn_readlane(myid, (j)) * 256 + lane * 4))

  for (int j0 = 0; j0 < n; j0 += 64) {
    const int m = min(n - j0, 64);
    const int myid = (lane < m) ? bucket_src[start + j0 + lane] : 0;
    const int nb = m & ~3;
    if (nb) {
      uint4 c0 = LDROW(0), c1 = LDROW(1), c2 = LDROW(2), c3 = LDROW(3);
      for (int j = 4; j < nb; j += 4) {
        const uint4 t0 = LDROW(j),     t1 = LDROW(j + 1);
        const uint4 t2 = LDROW(j + 2), t3 = LDROW(j + 3);
        acc16q(ac, c0); acc16q(ac, c1); acc16q(ac, c2); acc16q(ac, c3);
        c0 = t0; c1 = t1; c2 = t2; c3 = t3;
      }
      acc16q(ac, c0); acc16q(ac, c1); acc16q(ac, c2); acc16q(ac, c3);
    }
    for (int j = nb; j < m; ++j) {
      const uint4 x0 = LDROW(j);
      acc16q(ac, x0);
    }
  }
#undef LDROW

  const float inv = 1.0f / fmaxf((float)n, 1.0f);
  uint4 o0, o1;
  o0.x = (u32)f2bf(ac[0].x * inv) | ((u32)f2bf(ac[0].y * inv) << 16);
  o0.y = (u32)f2bf(ac[1].x * inv) | ((u32)f2bf(ac[1].y * inv) << 16);
  o0.z = (u32)f2bf(ac[2].x * inv) | ((u32)f2bf(ac[2].y * inv) << 16);
  o0.w = (u32)f2bf(ac[3].x * inv) | ((u32)f2bf(ac[3].y * inv) << 16);
  o1.x = (u32)f2bf(ac[4].x * inv) | ((u32)f2bf(ac[4].y * inv) << 16);
  o1.y = (u32)f2bf(ac[5].x * inv) | ((u32)f2bf(ac[5].y * inv) << 16);
  o1.z = (u32)f2bf(ac[6].x * inv) | ((u32)f2bf(ac[6].y * inv) << 16);
  o1.w = (u32)f2bf(ac[7].x * inv) | ((u32)f2bf(ac[7].y * inv) << 16);
  u16* dp = hcat + (size_t)node * KCAT + (size_t)r * DDIM + lane * 16;
  *(uint4*)(dp)     = o0;
  *(uint4*)(dp + 8) = o1;
}

// ---------------------------------------------------------------------------
// Shared GEMM machinery. R11: no forced lgkmcnt(0); FENCE after barriers.
// ---------------------------------------------------------------------------

#define MF16(a, b, c) __builtin_amdgcn_mfma_f32_16x16x32_bf16(a, b, c, 0, 0, 0)
#define MF32(a, b, c) __builtin_amdgcn_mfma_f32_32x32x16_bf16(a, b, c, 0, 0, 0)

#define FENCE asm volatile("" ::: "memory")

#define STAGE_A(t, p, b)                                                   \
  { GLD16(gA0 + (size_t)(t) * 64 + (size_t)(p) * KP,                       \
          &sA[b][(p) * 8192 + lofs0]);                                     \
    GLD16(gA1 + (size_t)(t) * 64 + (size_t)(p) * KP,                       \
          &sA[b][(p) * 8192 + lofs1]); }

#define STAGE_B(t, p, b)                                                   \
  { GLD16(gB0 + (size_t)(t) * 64 + (size_t)(p) * KP,                       \
          &sB[b][(p) * 8192 + lofs0]);                                     \
    GLD16(gB1 + (size_t)(t) * 64 + (size_t)(p) * KP,                       \
          &sB[b][(p) * 8192 + lofs1]); }

#define NOWAIT ((void)0)
#define NOSTAGE ((void)0)
#define NOB ((void)0)
#define VM6 asm volatile("s_waitcnt vmcnt(6)" ::: "memory")
#define VM4 asm volatile("s_waitcnt vmcnt(4)" ::: "memory")
#define VM2 asm volatile("s_waitcnt vmcnt(2)" ::: "memory")
#define VM0 asm volatile("s_waitcnt vmcnt(0)" ::: "memory")

// ---- gemm1 (32x32x16) machinery ----
// B register-capture: all 8 B-frags (2 ntiles x 4 ksteps) at phase 0, so
// phases 2-3 may overwrite this buffer's sB (same race analysis as before).
#define BVLOAD32(b)                                                        \
  { const bf16x8* pB_ = (const bf16x8*)sB[b];                              \
    bv[0][0] = pB_[brow8n0 + ((0 + lhi) ^ lx7)];                           \
    bv[1][0] = pB_[brow8n1 + ((0 + lhi) ^ lx7)];                           \
    bv[0][1] = pB_[brow8n0 + ((2 + lhi) ^ lx7)];                           \
    bv[1][1] = pB_[brow8n1 + ((2 + lhi) ^ lx7)];                           \
    bv[0][2] = pB_[brow8n0 + ((4 + lhi) ^ lx7)];                           \
    bv[1][2] = pB_[brow8n1 + ((4 + lhi) ^ lx7)];                           \
    bv[0][3] = pB_[brow8n0 + ((6 + lhi) ^ lx7)];                           \
    bv[1][3] = pB_[brow8n1 + ((6 + lhi) ^ lx7)]; }

// Phase Q = kstep Q: 4 A-frag reads (mtiles 0-3 at ks=Q), 8 independent MFMA.
#define PHASE32(Q, BUFI, OWNB, STAGE, ENDW)                                \
  { const bf16x8* pA_ = (const bf16x8*)sA[BUFI];                           \
    const int sq_ = (2 * (Q) + lhi) ^ lx7;                                 \
    bf16x8 a0 = pA_[arow80 + sq_];                                         \
    bf16x8 a1 = pA_[arow81 + sq_];                                         \
    bf16x8 a2 = pA_[arow82 + sq_];                                         \
    bf16x8 a3 = pA_[arow83 + sq_];                                         \
    OWNB;                                                                  \
    STAGE;                                                                 \
    __builtin_amdgcn_s_barrier();                                          \
    FENCE;                                                                 \
    __builtin_amdgcn_s_setprio(1);                                         \
    acc[0][0] = MF32(a0, bv[0][Q], acc[0][0]);                             \
    acc[0][1] = MF32(a0, bv[1][Q], acc[0][1]);                             \
    acc[1][0] = MF32(a1, bv[0][Q], acc[1][0]);                             \
    acc[1][1] = MF32(a1, bv[1][Q], acc[1][1]);                             \
    acc[2][0] = MF32(a2, bv[0][Q], acc[2][0]);                             \
    acc[2][1] = MF32(a2, bv[1][Q], acc[2][1]);                             \
    acc[3][0] = MF32(a3, bv[0][Q], acc[3][0]);                             \
    acc[3][1] = MF32(a3, bv[1][Q], acc[3][1]);                             \
    __builtin_amdgcn_s_setprio(0);                                         \
    ENDW;                                                                  \
    __builtin_amdgcn_s_barrier();                                          \
    FENCE; }

// ---- gemm2 (16x16x32) machinery (unchanged from R13) ----
#define BVLOAD(b)                                                          \
  { const bf16x8* pB_ = (const bf16x8*)sB[b];                              \
    bv[0][0] = pB_[brow80 + sega0]; bv[0][1] = pB_[brow80 + sega1];        \
    bv[1][0] = pB_[brow81 + sega0]; bv[1][1] = pB_[brow81 + sega1];        \
    bv[2][0] = pB_[brow82 + sega0]; bv[2][1] = pB_[brow82 + sega1];        \
    bv[3][0] = pB_[brow83 + sega0]; bv[3][1] = pB_[brow83 + sega1]; }

#define PHASE(Q, BUFI, STAGE, ENDW)                                        \
  { const bf16x8* pA_ = (const bf16x8*)sA[BUFI];                           \
    bf16x8 a00 = pA_[arow8[2 * (Q)] + sega0];                              \
    bf16x8 a01 = pA_[arow8[2 * (Q)] + sega1];                              \
    bf16x8 a10 = pA_[arow8[2 * (Q) + 1] + sega0];                          \
    bf16x8 a11 = pA_[arow8[2 * (Q) + 1] + sega1];                          \
    STAGE;                                                                 \
    __builtin_amdgcn_s_barrier();                                          \
    FENCE;                                                                 \
    __builtin_amdgcn_s_setprio(1);                                         \
    _Pragma("unroll")                                                      \
    for (int ni = 0; ni < 4; ++ni) {                                       \
      acc[2 * (Q)][ni]     = MF16(a00, bv[ni][0], acc[2 * (Q)][ni]);       \
      acc[2 * (Q)][ni]     = MF16(a01, bv[ni][1], acc[2 * (Q)][ni]);       \
      acc[2 * (Q) + 1][ni] = MF16(a10, bv[ni][0], acc[2 * (Q) + 1][ni]);   \
      acc[2 * (Q) + 1][ni] = MF16(a11, bv[ni][1], acc[2 * (Q) + 1][ni]);   \
    }                                                                      \
    __builtin_amdgcn_s_setprio(0);                                         \
    ENDW;                                                                  \
    __builtin_amdgcn_s_barrier();                                          \
    FENCE; }

// ---------------------------------------------------------------------------
// GEMM1: out1[8192x4096] = bf16(relu(hcat[8192x3072] @ WcatT^T + bias))
// R14: 256x256 tile, BK=64, 512 thr / 8 waves (2Mx4N, 128x64/wave), 128 KiB
// dbuf LDS, 8-phase counted-vmcnt schedule (VM4 at phases 4/8) — now with
// v_mfma_f32_32x32x16_bf16: per wave 4x2 tiles of 32x32, acc f32x16[4][2],
// phase Q = kstep Q (8 independent MFMA), B captured at phase 0 (bv[2][4]).
// Epilogue: C/D row=(r&3)+8*(r>>2)+4*(l>>5), col=l&31 -> LDS -> dwordx4.
// ---------------------------------------------------------------------------
__global__ __launch_bounds__(512) void gemm1_kernel(
    const u16* __restrict__ A, const u16* __restrict__ Bt,
    const float* __restrict__ bias, u16* __restrict__ obf) {
  const int K = KCAT, N = FDIM;
  const int NT = K / 64;                    // 48 K-tiles
  const size_t KP = (size_t)128 * K;        // piece-1 global row offset
  __shared__ __align__(16) u16 smem[65536];   // 128 KB
  u16 (*sA)[16384] = (u16(*)[16384])(smem);          // 2 bufs x 256x64 bf16
  u16 (*sB)[16384] = (u16(*)[16384])(smem + 32768);  // 2 bufs x 256x64 bf16

  const int tid  = threadIdx.x;
  const int lane = tid & 63;
  const int wave = tid >> 6;
  const int wr = wave >> 2, wc = wave & 3;    // 2 x 4 wave grid
  const int l31 = lane & 31;
  const int lhi = lane >> 5;                  // 0/1: K-half within frag
  const int lx7 = lane & 7;                   // row&7 (rows = l31 mod 32)

  const int bid = blockIdx.x;
  const int swz = (bid & 7) * 64 + (bid >> 3);
  const int bm = (swz >> 4) * 256;
  const int bn = (swz & 15) * 256;

  int lofs0, lofs1;
  const u16 *gA0, *gA1, *gB0, *gB1;
  {
    const int s0 = tid,       r0 = s0 >> 3, g0 = (s0 & 7) ^ (r0 & 7);
    const int s1 = tid + 512, r1 = s1 >> 3, g1 = (s1 & 7) ^ (r1 & 7);
    gA0 = A  + (size_t)(bm + r0) * K + g0 * 8;
    gA1 = A  + (size_t)(bm + r1) * K + g1 * 8;
    gB0 = Bt + (size_t)(bn + r0) * K + g0 * 8;
    gB1 = Bt + (size_t)(bn + r1) * K + g1 * 8;
    lofs0 = s0 * 8; lofs1 = s1 * 8;
  }

  // fragment row bases (bf16x8 units); row&7 == lane&7 for all (32 | tiles)
  const int arow80 = (wr * 128 +  0 + l31) * 8;
  const int arow81 = (wr * 128 + 32 + l31) * 8;
  const int arow82 = (wr * 128 + 64 + l31) * 8;
  const int arow83 = (wr * 128 + 96 + l31) * 8;
  const int brow8n0 = (wc * 64 +  0 + l31) * 8;
  const int brow8n1 = (wc * 64 + 32 + l31) * 8;

  f32x16 acc[4][2] = {};
  bf16x8 bv[2][4];

  STAGE_B(0, 0, 0) STAGE_B(0, 1, 0)
  STAGE_A(0, 0, 0) STAGE_A(0, 1, 0)
  STAGE_B(1, 0, 1) STAGE_B(1, 1, 1)
  asm volatile("s_waitcnt vmcnt(4)" ::: "memory");
  __builtin_amdgcn_s_barrier();
  FENCE;

  for (int tt = 0; tt < NT - 2; tt += 2) {
    PHASE32(0, 0, BVLOAD32(0), STAGE_A(tt + 1, 0, 1), NOWAIT)
    PHASE32(1, 0, NOB,         STAGE_A(tt + 1, 1, 1), NOWAIT)
    PHASE32(2, 0, NOB,         STAGE_B(tt + 2, 0, 0), NOWAIT)
    PHASE32(3, 0, NOB,         STAGE_B(tt + 2, 1, 0), VM4)
    PHASE32(0, 1, BVLOAD32(1), STAGE_A(tt + 2, 0, 0), NOWAIT)
    PHASE32(1, 1, NOB,         STAGE_A(tt + 2, 1, 0), NOWAIT)
    PHASE32(2, 1, NOB,         STAGE_B(tt + 3, 0, 1), NOWAIT)
    PHASE32(3, 1, NOB,         STAGE_B(tt + 3, 1, 1), VM4)
  }
  PHASE32(0, 0, BVLOAD32(0), STAGE_A(NT - 1, 0, 1), NOWAIT)
  PHASE32(1, 0, NOB,         STAGE_A(NT - 1, 1, 1), NOWAIT)
  PHASE32(2, 0, NOB,         NOSTAGE, NOWAIT)
  PHASE32(3, 0, NOB,         NOSTAGE, VM0)
  PHASE32(0, 1, BVLOAD32(1), NOSTAGE, NOWAIT)
  PHASE32(1, 1, NOB,         NOSTAGE, NOWAIT)
  PHASE32(2, 1, NOB,         NOSTAGE, NOWAIT)
  PHASE32(3, 1, NOB,         NOSTAGE, NOWAIT)

  // --- epilogue: bias+relu+f2bf -> LDS [128][264] -> dwordx4 stores ---
  const int CPAD = 264;                       // 264*2B row pitch: 16B-aligned
  const float bb0 = bias[bn + wc * 64 + l31];
  const float bb1 = bias[bn + wc * 64 + 32 + l31];
  const int ecol0 = wc * 64 + l31;
#pragma unroll
  for (int h = 0; h < 2; ++h) {
    if (wr == h) {
#pragma unroll
      for (int mi = 0; mi < 4; ++mi) {
#pragma unroll
        for (int ni = 0; ni < 2; ++ni) {
          const float bb = ni ? bb1 : bb0;
          const int col = ecol0 + ni * 32;
#pragma unroll
          for (int r = 0; r < 16; ++r) {
            const int lrow = mi * 32 + (r & 3) + 8 * (r >> 2) + 4 * lhi;
            const float v = acc[mi][ni][r] + bb;
            smem[lrow * CPAD + col] = f2bf(fmaxf(v, 0.0f));
          }
        }
      }
    }
    __syncthreads();
#pragma unroll
    for (int i = 0; i < 8; ++i) {
      const int chunk = tid + 512 * i;        // 4096 chunks of 16B
      const int row = chunk >> 5;             // 0..127
      const int seg = chunk & 31;             // 0..31
      const uint4 val = *(const uint4*)(smem + row * CPAD + seg * 8);
      *(uint4*)(obf + (size_t)(bm + h * 128 + row) * N + bn + seg * 8) = val;
    }
    __syncthreads();
  }
}

// ---------------------------------------------------------------------------
// GEMM2: out[8192x1024] = resid + out1[8192x4096] @ woT^T
// R13: 256x128 tile, triple-buffered (144KB), stage-2-ahead, VM6 per K-tile.
// ---------------------------------------------------------------------------
__global__ __launch_bounds__(512) void gemm2_kernel(
    const u16* __restrict__ A, const u16* __restrict__ Bt,
    const float* __restrict__ resid, float* __restrict__ out) {
  const int K = FDIM, N = DDIM;
  const int NT = K / 64;                    // 64 K-tiles
  const size_t KP = (size_t)128 * K;        // piece-1 global row offset
  __shared__ __align__(16) u16 smem[73728];   // 144 KB
  u16 (*sA)[16384] = (u16(*)[16384])(smem);           // 3 bufs x 256x64
  u16 (*sB)[8192]  = (u16(*)[8192])(smem + 49152);    // 3 bufs x 128x64

  const int tid  = threadIdx.x;
  const int lane = tid & 63;
  const int wave = tid >> 6;
  const int wr = wave >> 1, wc = wave & 1;    // 4 x 2 wave grid (64x64/wave)
  const int lr = lane & 15, quad = lane >> 4;

  const int bid = blockIdx.x;
  const int swz = (bid & 7) * 32 + (bid >> 3);
  const int bm = (swz >> 3) * 256;
  const int bn = (swz & 7) * 128;

  int lofs0, lofs1;
  const u16 *gA0, *gA1, *gB0, *gB1;
  {
    const int s0 = tid,       r0 = s0 >> 3, g0 = (s0 & 7) ^ (r0 & 7);
    const int s1 = tid + 512, r1 = s1 >> 3, g1 = (s1 & 7) ^ (r1 & 7);
    gA0 = A  + (size_t)(bm + r0) * K + g0 * 8;
    gA1 = A  + (size_t)(bm + r1) * K + g1 * 8;
    gB0 = Bt + (size_t)(bn + r0) * K + g0 * 8;   // B rows 0..63 (slot tid)
    gB1 = Bt + (size_t)(bn + r1) * K + g1 * 8;   // B rows 64..127 (tid+512)
    lofs0 = s0 * 8; lofs1 = s1 * 8;
  }

  int arow8[4];
#pragma unroll
  for (int mi = 0; mi < 4; ++mi) arow8[mi] = (wr * 64 + mi * 16 + lr) * 8;
  const int brow80 = (wc * 64 +  0 + lr) * 8;
  const int brow81 = (wc * 64 + 16 + lr) * 8;
  const int brow82 = (wc * 64 + 32 + lr) * 8;
  const int brow83 = (wc * 64 + 48 + lr) * 8;
  const int sega0 = quad ^ (lr & 7);
  const int sega1 = (4 + quad) ^ (lr & 7);

  f32x4 acc[4][4] = {};
  bf16x8 bv[4][2];

  // prologue: tiles 0 (buf0) and 1 (buf1), 6 loads each; VM6 -> tile0 landed.
  STAGE_B(0, 0, 0) STAGE_A(0, 0, 0) STAGE_A(0, 1, 0)
  STAGE_B(1, 0, 1) STAGE_A(1, 0, 1) STAGE_A(1, 1, 1)
  VM6;
  __builtin_amdgcn_s_barrier();
  FENCE;

  for (int tt = 0; tt < NT - 4; tt += 3) {     // tt = 0,3,...,57
    PHASE(0, 0, BVLOAD(0); STAGE_A(tt + 2, 0, 2), NOWAIT)
    PHASE(1, 0, STAGE_A(tt + 2, 1, 2); STAGE_B(tt + 2, 0, 2), VM6)
    PHASE(0, 1, BVLOAD(1); STAGE_A(tt + 3, 0, 0), NOWAIT)
    PHASE(1, 1, STAGE_A(tt + 3, 1, 0); STAGE_B(tt + 3, 0, 0), VM6)
    PHASE(0, 2, BVLOAD(2); STAGE_A(tt + 4, 0, 1), NOWAIT)
    PHASE(1, 2, STAGE_A(tt + 4, 1, 1); STAGE_B(tt + 4, 0, 1), VM6)
  }
  // tail: tiles 60(b0), 61(b1), 62(b2), 63(b0); staged through 61.
  PHASE(0, 0, BVLOAD(0); STAGE_A(NT - 2, 0, 2), NOWAIT)
  PHASE(1, 0, STAGE_A(NT - 2, 1, 2); STAGE_B(NT - 2, 0, 2), VM6)
  PHASE(0, 1, BVLOAD(1); STAGE_A(NT - 1, 0, 0), NOWAIT)
  PHASE(1, 1, STAGE_A(NT - 1, 1, 0); STAGE_B(NT - 1, 0, 0), VM6)
  PHASE(0, 2, BVLOAD(2), NOWAIT)
  PHASE(1, 2, NOSTAGE, VM0)
  PHASE(0, 0, BVLOAD(0), NOWAIT)
  PHASE(1, 0, NOSTAGE, NOWAIT)

  // --- epilogue: acc -> LDS f32 [128][132] -> float4 resid+store ---
  float* smemf = (float*)smem;
  const int FPAD = 132;                     // 132*4B pitch: 16B-aligned
#pragma unroll
  for (int h = 0; h < 2; ++h) {
    __syncthreads();
    if ((wr >> 1) == h) {
#pragma unroll
      for (int mi = 0; mi < 4; ++mi) {
        const int srow0 = (wr & 1) * 64 + mi * 16 + quad * 4;
#pragma unroll
        for (int ni = 0; ni < 4; ++ni) {
          const int scol = wc * 64 + ni * 16 + lr;
#pragma unroll
          for (int r = 0; r < 4; ++r)
            smemf[(srow0 + r) * FPAD + scol] = acc[mi][ni][r];
        }
      }
    }
    __syncthreads();
#pragma unroll
    for (int i = 0; i < 8; ++i) {
      const int chunk = tid + 512 * i;        // 4096 chunks of 16B
      const int row = chunk >> 5;             // 0..127
      const int seg = chunk & 31;             // 0..31
      const float4 lv = *(const float4*)(smemf + row * FPAD + seg * 4);
      const size_t gofs = (size_t)(bm + h * 128 + row) * N + bn + seg * 4;
      const float4 rv = *(const float4*)(resid + gofs);
      float4 ov;
      ov.x = rv.x + lv.x; ov.y = rv.y + lv.y;
      ov.z = rv.z + lv.z; ov.w = rv.w + lv.w;
      *(float4*)(out + gofs) = ov;
    }
  }
}

// ---------------------------------------------------------------------------
// Workspace layout: unchanged (144 MB total; see R13 header).
// ---------------------------------------------------------------------------
extern "C" void kernel_launch(void* const* d_in, const int* in_sizes, int n_in,
                              void* d_out, int out_size, void* d_ws, size_t ws_size,
                              hipStream_t stream) {
  const float* hs     = (const float*)d_in[0];
  const float* weight = (const float*)d_in[1];   // [2,1024,4096]
  const float* root   = (const float*)d_in[2];   // [1024,4096]
  const float* bias   = (const float*)d_in[3];   // [4096]
  const float* wo     = (const float*)d_in[4];   // [4096,1024]
  const float* gamma  = (const float*)d_in[5];
  const float* beta   = (const float*)d_in[6];
  const int* edge_index = (const int*)d_in[7];   // [2,E]
  const int* edge_type  = (const int*)d_in[8];   // [E]
  float* out = (float*)d_out;

  char* ws = (char*)d_ws;
  u16*   hcat       = (u16*)(ws + 0);
  u16*   WcatT      = (u16*)(ws + 50331648);
  u16*   woT        = (u16*)(ws + 75497472);
  u16*   out1       = (u16*)(ws + 83886080);
  int*   bucket_src = (int*)(ws + 83886080);     // aliases out1 (consumed pre-GEMM1)
  int*   cnt        = (int*)(ws + 84934656);
  int*   off        = (int*)(ws + 85000192);
  int*   cursor     = (int*)(ws + 85065728);
  u32*   xq         = (u32*)(ws + 85131264);     // fp8 x, dense [8192][1024]

  (void)hipMemsetAsync(cnt, 0, 65536, stream);

  // LN + fused edge count
  ln_kernel<<<NNODE, 256, 0, stream>>>(hs, gamma, beta, hcat, xq,
                                       edge_index, edge_type, cnt);

  scan_kernel<<<1, 1024, 0, stream>>>(cnt, off, cursor);
  fill_kernel<<<E_NUM / 256, 256, 0, stream>>>(edge_index, edge_type, cursor, bucket_src);

  // fused: aggregate (L3 gather) + both weight transposes (HBM) overlap
  agg_cvt_kernel<<<AGG_BLOCKS + CVT1_BLOCKS + CVT2_BLOCKS, 256, 0, stream>>>(
      cnt, off, bucket_src, xq, hcat, weight, root, WcatT, wo, woT);

  // out1 = relu([h0|h1|x] @ [W0;W1;root] + bias)   [8192 x 4096] bf16
  gemm1_kernel<<<512, 512, 0, stream>>>(hcat, WcatT, bias, out1);

  // out = hs + out1 @ wo                            [8192 x 1024] f32
  gemm2_kernel<<<256, 512, 0, stream>>>(out1, woT, hs, out);
}